// Round 10
// baseline (2204.334 us; speedup 1.0000x reference)
//
#include <hip/hip_runtime.h>
#include <math.h>
#include <stdint.h>

#define Lr 32
#define Hh 128
#define NCELL 1024
#define NEPS 1e-8f
#define CELLB 33792            // 33 chunks x 64 lanes x 16 B per cell

typedef _Float16 f16;
typedef f16 h2 __attribute__((ext_vector_type(2)));
typedef uint32_t u32;
typedef u32 u32x4 __attribute__((ext_vector_type(4)));

#define GLOBAL_AS __attribute__((address_space(1)))
#define LDS_AS    __attribute__((address_space(3)))

__device__ __forceinline__ h2 bch2(u32 v) {
    union { u32 u; h2 h; } c; c.u = v; return c.h;
}
__device__ __forceinline__ float h16(u32 wd, int hi) {
    union { unsigned short u; f16 h; } c;
    c.u = (unsigned short)(hi ? (wd >> 16) : (wd & 0xffff));
    return (float)c.h;
}
__device__ __forceinline__ u32 packh2(float a, float b) {
    union { u32 u; f16 h[2]; } c; c.h[0] = (f16)a; c.h[1] = (f16)b; return c.u;
}
__device__ __forceinline__ float dot2(h2 a, h2 b, float c) {
    return __builtin_amdgcn_fdot2(a, b, c, false);   // v_dot2_f32_f16
}
template<int CTRL>
__device__ __forceinline__ float dpp_get(float x) {
    return __int_as_float(__builtin_amdgcn_update_dpp(
        0, __float_as_int(x), CTRL, 0xf, 0xf, true));
}
// 0xB1=xor1 quad_perm, 0x4E=xor2 quad_perm, 0x141=row_half_mirror, 0x140=row_mirror
__device__ __forceinline__ float rlane(float x, int l) {
    return __int_as_float(__builtin_amdgcn_readlane(__float_as_int(x), l));
}
__device__ __forceinline__ float fast_tanh(float x) {
    x = fminf(9.f, fmaxf(-9.f, x));
    const float e = __expf(2.f * x);
    return 1.f - 2.f / (e + 1.f);
}
__device__ __forceinline__ int cell_of(int s) {
    const int i = s >> 5, j = s & 31;
    const int c = (i & 1) ? (Lr - 1 - j) : j;
    return i * Lr + c;
}

// W1[cell][k][m] (fp32, k<128, m:0,1=spin cols, 2..129=h cols) -> 33KB image:
// lane l owns k0=2l, k1=2l+1.
//  chunks q=0..31: [q][l] 16B u32x4 = { w(k0,2q), w(k1,2q), w(k0,2q+1),
//    w(k1,2q+1) } where w(k,p)=pack_f16(W[k][2+2p], W[k][3+2p]).
//  chunk 32 (tail): [l] 16B = { pack(t0(k0),t0(k1)), pack(t1..), pack(t2..),
//    pack(wf(k0),wf(k1)) }; binary spins fold spin-cols+bias into candidates
//    t0=2W[k][1]+2b, t1=W[k][0]+W[k][1]+2b, t2=2W[k][0]+2b.
__global__ __launch_bounds__(256)
void transpose_w(const float* __restrict__ W1, const float* __restrict__ b1,
                 const float* __restrict__ Wf, char* __restrict__ Wt) {
    __shared__ float tile[Hh * 130];    // 66.6 KB
    const int cell = blockIdx.x;
    const float* src = W1 + (size_t)cell * (Hh * 130);
    for (int idx = threadIdx.x; idx < Hh * 130; idx += 256) tile[idx] = src[idx];
    __syncthreads();
    char* dst = Wt + (size_t)cell * CELLB;
    for (int idx = threadIdx.x; idx < 2048; idx += 256) {
        const int q = idx >> 6, l = idx & 63;
        const int k0 = 2 * l, k1 = 2 * l + 1;
        const int p0 = 2 * q, p1 = 2 * q + 1;
        union { u32x4 v; f16 h[8]; } o;
        o.h[0] = (f16)tile[k0 * 130 + 2 + 2 * p0];
        o.h[1] = (f16)tile[k0 * 130 + 3 + 2 * p0];
        o.h[2] = (f16)tile[k1 * 130 + 2 + 2 * p0];
        o.h[3] = (f16)tile[k1 * 130 + 3 + 2 * p0];
        o.h[4] = (f16)tile[k0 * 130 + 2 + 2 * p1];
        o.h[5] = (f16)tile[k0 * 130 + 3 + 2 * p1];
        o.h[6] = (f16)tile[k1 * 130 + 2 + 2 * p1];
        o.h[7] = (f16)tile[k1 * 130 + 3 + 2 * p1];
        *(u32x4*)(dst + q * 1024 + l * 16) = o.v;
    }
    if (threadIdx.x < 64) {
        const int l = threadIdx.x, k0 = 2 * l, k1 = 2 * l + 1;
        const float b0 = 2.f * b1[cell * Hh + k0], b1v = 2.f * b1[cell * Hh + k1];
        union { u32x4 v; f16 h[8]; } o;
        o.h[0] = (f16)(2.f * tile[k0 * 130 + 1] + b0);
        o.h[1] = (f16)(2.f * tile[k1 * 130 + 1] + b1v);
        o.h[2] = (f16)(tile[k0 * 130 + 0] + tile[k0 * 130 + 1] + b0);
        o.h[3] = (f16)(tile[k1 * 130 + 0] + tile[k1 * 130 + 1] + b1v);
        o.h[4] = (f16)(2.f * tile[k0 * 130 + 0] + b0);
        o.h[5] = (f16)(2.f * tile[k1 * 130 + 0] + b1v);
        o.h[6] = (f16)Wf[cell * Hh + k0];
        o.h[7] = (f16)Wf[cell * Hh + k1];
        *(u32x4*)(dst + 32 * 1024 + l * 16) = o.v;
    }
}

// 256 blocks x ONE wave x TWO batch elements; 1 block/CU. Zero barriers:
// the whole recurrence is in-wave (same-wave DS ops execute in order).
// Lane l owns outputs k=2l,2l+1 for both elements; each staged weight chunk
// is read once from LDS and dotted twice. Weights stream through an LDS
// double-buffer filled by global_load_lds (NO register destination -> the
// register allocator cannot corrupt the prefetch, unlike rounds 8/9 where
// 132-264 asm-tied in-flight VGPRs got phi-copied/spilled as garbage),
// retired by counted s_waitcnt vmcnt(33) — never a drain.
__global__ __launch_bounds__(64, 1)
void rnn2d(const float* __restrict__ samples,
           const char* __restrict__ Wt,
           const float* __restrict__ bfv,
           float* __restrict__ out)
{
    __shared__ __align__(16) u32 wl[2][8448];   // 67.6 KB weight double-buffer
    __shared__ u32   hvp[2][64 * 33];           // h_v pairs [elem][l*33+col]
    __shared__ __align__(16) u32 xpb[2][64];    // input-pair exchange [elem]
    __shared__ float smpE[2][NCELL];            // spins per element
    __shared__ float bfL[NCELL];                // head bias

    const int t  = threadIdx.x;                 // lane 0..63
    const int t4 = t * 4;
    const int b0 = blockIdx.x * 2;

    for (int q = 0; q < 16; ++q) {
        smpE[0][q * 64 + t] = samples[(size_t)b0 * NCELL + q * 64 + t];
        smpE[1][q * 64 + t] = samples[(size_t)(b0 + 1) * NCELL + q * 64 + t];
        bfL[q * 64 + t] = bfv[q * 64 + t];
    }
    for (int c = 0; c < 33; ++c) { hvp[0][t * 33 + c] = 0; hvp[1][t * 33 + c] = 0; }
    xpb[0][t] = 0; xpb[1][t] = 0;
    // drain the sample loads so in-loop vmcnt counts ONLY weight stages
    asm volatile("s_waitcnt vmcnt(0)" ::: "memory");

    u32x4 xa[16], xc[16];                       // current-cell input pairs
#pragma unroll
    for (int r = 0; r < 16; ++r) { xa[r] = (u32x4)0; xc[r] = (u32x4)0; }
    float lp0 = 0.f, lp1 = 0.f;

// stage cell S's 33KB into LDS buffer P (33 async 1KB row copies)
#define STAGE(S, P)                                                         \
    {                                                                       \
        const int s_ = ((S) < NCELL) ? (S) : 0;                             \
        const char* cb_ = Wt + (size_t)cell_of(s_) * CELLB;                 \
        _Pragma("unroll")                                                   \
        for (int q_ = 0; q_ < 33; ++q_)                                     \
            __builtin_amdgcn_global_load_lds(                               \
                (const GLOBAL_AS u32*)(cb_ + q_ * 1024 + t * 16),           \
                (LDS_AS u32*)&wl[P][q_ * 256 + t4], 16, 0, 0);              \
    }

// counted wait: retire the older stage (33 ops), keep the newer in flight
#define WAITW()                                                             \
    asm volatile("s_waitcnt vmcnt(33)" ::: "memory");                       \
    __builtin_amdgcn_sched_barrier(0);

#define PROC(S, Q)                                                          \
    {                                                                       \
        STAGE((S) + 1, (Q) ^ 1)        /* issue next stage first */         \
        const int i_ = (S) >> 5, j_ = (S) & 31;                             \
        const int c_ = (i_ & 1) ? (Lr - 1 - j_) : j_;                       \
        const int sn_ = ((S) + 1 < NCELL) ? (S) + 1 : (S);                  \
        const int in_ = sn_ >> 5, jn_ = sn_ & 31;                           \
        const int cn_ = (in_ & 1) ? (Lr - 1 - jn_) : jn_;                   \
        const int cc_ = i_ * Lr + c_;                                       \
        const u32 hvn0 = hvp[0][t * 33 + cn_];                              \
        const u32 hvn1 = hvp[1][t * 33 + cn_];                              \
        const int il_ = (j_ > 0) ? cell_of((S) - 1) : 0;                    \
        const float sl0 = (j_ > 0) ? smpE[0][il_] : 0.f;                    \
        const float sl1 = (j_ > 0) ? smpE[1][il_] : 0.f;                    \
        const float sa0 = (i_ > 0) ? smpE[0][(i_ - 1) * Lr + c_] : 0.f;     \
        const float sa1 = (i_ > 0) ? smpE[1][(i_ - 1) * Lr + c_] : 0.f;     \
        const float bfc = bfL[cc_];                                         \
        const float m0 = smpE[0][cc_], m1 = smpE[1][cc_];                   \
        const int cse0 = (int)(sl0 + sa0), cse1 = (int)(sl1 + sa1);         \
        WAITW()                                                             \
        /* 2-element dot: each staged chunk read once, dotted twice */      \
        float p0=0.f,p1=0.f,p2=0.f,p3=0.f;  /* elem0 k0/k1, chains A/B */   \
        float r0=0.f,r1=0.f,r2=0.f,r3=0.f;  /* elem1 */                     \
        _Pragma("unroll")                                                   \
        for (int q_ = 0; q_ < 32; ++q_) {                                   \
            const u32x4 wq = *(const u32x4*)&wl[Q][q_ * 256 + t4];          \
            const u32x4 ua = xa[q_ >> 1];                                   \
            const u32x4 uc = xc[q_ >> 1];                                   \
            const h2 ua0 = bch2(ua[(q_ & 1) * 2]);                          \
            const h2 ua1 = bch2(ua[(q_ & 1) * 2 + 1]);                      \
            const h2 uc0 = bch2(uc[(q_ & 1) * 2]);                          \
            const h2 uc1 = bch2(uc[(q_ & 1) * 2 + 1]);                      \
            if ((q_ & 1) == 0) {                                            \
                p0 = dot2(bch2(wq[0]), ua0, p0);                            \
                p1 = dot2(bch2(wq[1]), ua0, p1);                            \
                p0 = dot2(bch2(wq[2]), ua1, p0);                            \
                p1 = dot2(bch2(wq[3]), ua1, p1);                            \
                r0 = dot2(bch2(wq[0]), uc0, r0);                            \
                r1 = dot2(bch2(wq[1]), uc0, r1);                            \
                r0 = dot2(bch2(wq[2]), uc1, r0);                            \
                r1 = dot2(bch2(wq[3]), uc1, r1);                            \
            } else {                                                        \
                p2 = dot2(bch2(wq[0]), ua0, p2);                            \
                p3 = dot2(bch2(wq[1]), ua0, p3);                            \
                p2 = dot2(bch2(wq[2]), ua1, p2);                            \
                p3 = dot2(bch2(wq[3]), ua1, p3);                            \
                r2 = dot2(bch2(wq[0]), uc0, r2);                            \
                r3 = dot2(bch2(wq[1]), uc0, r3);                            \
                r2 = dot2(bch2(wq[2]), uc1, r2);                            \
                r3 = dot2(bch2(wq[3]), uc1, r3);                            \
            }                                                               \
        }                                                                   \
        const u32x4 tl = *(const u32x4*)&wl[Q][8192 + t4];                  \
        u32 tt0 = tl[0]; if (cse0 == 1) tt0 = tl[1]; if (cse0 == 2) tt0 = tl[2]; \
        u32 tt1 = tl[0]; if (cse1 == 1) tt1 = tl[1]; if (cse1 == 2) tt1 = tl[2]; \
        const float h00 = fast_tanh(p0 + p2 + h16(tt0, 0));                 \
        const float h01 = fast_tanh(p1 + p3 + h16(tt0, 1));                 \
        const float h10 = fast_tanh(r0 + r2 + h16(tt1, 0));                 \
        const float h11 = fast_tanh(r1 + r3 + h16(tt1, 1));                 \
        /* in-wave exchange FIRST (recurrence-critical), head/lp after */   \
        if ((S) + 1 < NCELL) {                                              \
            const float v00 = ((jn_ == 0) ? 0.f : h00)                      \
                            + ((cn_ == c_) ? h00 : h16(hvn0, 0));           \
            const float v01 = ((jn_ == 0) ? 0.f : h01)                      \
                            + ((cn_ == c_) ? h01 : h16(hvn0, 1));           \
            const float v10 = ((jn_ == 0) ? 0.f : h10)                      \
                            + ((cn_ == c_) ? h10 : h16(hvn1, 0));           \
            const float v11 = ((jn_ == 0) ? 0.f : h11)                      \
                            + ((cn_ == c_) ? h11 : h16(hvn1, 1));           \
            xpb[0][t] = packh2(v00, v01);                                   \
            xpb[1][t] = packh2(v10, v11);                                   \
            _Pragma("unroll")                                               \
            for (int r_ = 0; r_ < 16; ++r_) {                               \
                xa[r_] = *(const u32x4*)&xpb[0][r_ * 4];                    \
                xc[r_] = *(const u32x4*)&xpb[1][r_ * 4];                    \
            }                                                               \
        }                                                                   \
        hvp[0][t * 33 + c_] = packh2(h00, h01);                             \
        hvp[1][t * 33 + c_] = packh2(h10, h11);                             \
        /* head: 64-sum via DPP chain (valid on lanes 0-15; lane 0 used) */ \
        const float wf0 = h16(tl[3], 0), wf1 = h16(tl[3], 1);               \
        float f0 = fmaf(h00, wf0, h01 * wf1);                               \
        float f1 = fmaf(h10, wf0, h11 * wf1);                               \
        f0 += dpp_get<0xB1>(f0);  f1 += dpp_get<0xB1>(f1);                  \
        f0 += dpp_get<0x4E>(f0);  f1 += dpp_get<0x4E>(f1);                  \
        f0 += dpp_get<0x141>(f0); f1 += dpp_get<0x141>(f1);                 \
        f0 += dpp_get<0x140>(f0); f1 += dpp_get<0x140>(f1);                 \
        f0 = f0 + rlane(f0, 16) + rlane(f0, 32) + rlane(f0, 48);            \
        f1 = f1 + rlane(f1, 16) + rlane(f1, 32) + rlane(f1, 48);            \
        const float xh0 = 1.f / (1.f + __expf(-(f0 + bfc)));                \
        const float xh1 = 1.f / (1.f + __expf(-(f1 + bfc)));                \
        lp0 += __logf((m0 > 0.5f) ? (xh0 + NEPS) : (1.f - xh0 + NEPS));     \
        lp1 += __logf((m1 > 0.5f) ? (xh1 + NEPS) : (1.f - xh1 + NEPS));     \
    }

    STAGE(0, 0)
    for (int s = 0; s < NCELL; s += 2) {
        PROC(s, 0);
        PROC(s + 1, 1);
    }
#undef STAGE
#undef WAITW
#undef PROC

    if (t == 0) {
        out[b0]     = lp0;
        out[b0 + 1] = lp1;
    }
}

extern "C" void kernel_launch(void* const* d_in, const int* in_sizes, int n_in,
                              void* d_out, int out_size, void* d_ws, size_t ws_size,
                              hipStream_t stream) {
    const float* samples = (const float*)d_in[0];
    const float* W1      = (const float*)d_in[1];
    const float* b1      = (const float*)d_in[2];
    const float* Wf      = (const float*)d_in[3];
    const float* bf      = (const float*)d_in[4];
    float* outp = (float*)d_out;
    char* Wt = (char*)d_ws;   // 1024 * 33792 B = 34.6 MB

    transpose_w<<<1024, 256, 0, stream>>>(W1, b1, Wf, Wt);
    rnn2d<<<256, 64, 0, stream>>>(samples, Wt, bf, outp);
}

// Round 11
// 861.538 us; speedup vs baseline: 2.5586x; 2.5586x over previous
//
#include <hip/hip_runtime.h>
#include <math.h>
#include <stdint.h>

#define Lr 32
#define Hh 128
#define NCELL (Lr * Lr)
#define NEPS 1e-8f
#define CELLB 33792            // bytes per cell image: 4x8KB pair-chunks + 1KB tail

typedef _Float16 f16;
typedef f16 h2 __attribute__((ext_vector_type(2)));
typedef uint32_t u32;
typedef u32 u32x4 __attribute__((ext_vector_type(4)));
typedef u32 u32x2 __attribute__((ext_vector_type(2)));

// LDS-publish barrier (does NOT touch vmcnt: in-flight weight loads survive).
__device__ __forceinline__ void bar_lds() {
    asm volatile("s_waitcnt lgkmcnt(0)\n\ts_barrier" ::: "memory");
}

template<int CTRL>
__device__ __forceinline__ float dpp_get(float x) {
    return __int_as_float(__builtin_amdgcn_update_dpp(
        0, __float_as_int(x), CTRL, 0xf, 0xf, true));
}
// 0xB1 = quad_perm[1,0,3,2] (xor1), 0x4E = quad_perm[2,3,0,1] (xor2),
// 0x141 = row_half_mirror, 0x140 = row_mirror

__device__ __forceinline__ float rlane(float x, int l) {
    return __int_as_float(__builtin_amdgcn_readlane(__float_as_int(x), l));
}

__device__ __forceinline__ float dot2(h2 a, h2 b, float c) {
    return __builtin_amdgcn_fdot2(a, b, c, false);   // v_dot2_f32_f16
}

__device__ __forceinline__ h2 bch2(u32 v) {
    union { u32 u; h2 h; } cv; cv.u = v; return cv.h;
}
__device__ __forceinline__ float h16(u32 w, int hi) {
    union { unsigned short u; f16 h; } c;
    c.u = (unsigned short)(hi ? (w >> 16) : (w & 0xffff));
    return (float)c.h;
}

__device__ __forceinline__ float fast_tanh(float x) {
    x = fminf(9.f, fmaxf(-9.f, x));
    const float e = __expf(2.f * x);
    return 1.f - 2.f / (e + 1.f);
}

__device__ __forceinline__ int cell_of(int s) {
    const int i = s >> 5, jj = s & 31;
    const int c = (i & 1) ? (Lr - 1 - jj) : jj;
    return i * Lr + c;
}

// W1[cell][k][m] (fp32, k<128, m:0,1=spin cols, 2..129=h cols) -> 33KB image:
//  chunk region (32KB): [q4<8][t<256] 16B = 4 f16-pairs; thread t (k=t>>1,
//    half=t&1) owns h-pairs p = half*32+q4*4+{0..3} = W cols (2+2p, 3+2p).
//  tail region (1KB): [k<128] 8B = f16 {sp0,sp1,sp2,wf}: binary spins fold
//    spin-cols+bias to 3 candidates: sp0=2W[k][1]+2b, sp1=W[k][0]+W[k][1]+2b,
//    sp2=2W[k][0]+2b.
__global__ __launch_bounds__(256)
void transpose_w(const float* __restrict__ W1, const float* __restrict__ b1,
                 const float* __restrict__ Wf, char* __restrict__ Wt) {
    __shared__ float tile[Hh * 130];    // 66.6 KB
    const int cell = blockIdx.x;
    const float* src = W1 + (size_t)cell * (Hh * 130);
    for (int idx = threadIdx.x; idx < Hh * 130; idx += 256)
        tile[idx] = src[idx];
    __syncthreads();
    char* dst = Wt + (size_t)cell * CELLB;
    const int t = threadIdx.x, kk = t >> 1, hf = t & 1;
    for (int q4 = 0; q4 < 8; ++q4) {
        union { u32x4 v; f16 h[8]; } o;
        for (int j = 0; j < 4; ++j) {
            const int p = hf * 32 + q4 * 4 + j;
            o.h[2 * j]     = (f16)tile[kk * 130 + 2 + 2 * p];
            o.h[2 * j + 1] = (f16)tile[kk * 130 + 3 + 2 * p];
        }
        *(u32x4*)(dst + q4 * 4096 + t * 16) = o.v;
    }
    if (t < Hh) {
        union { u32x2 v; f16 h[4]; } o;
        const float w0 = tile[t * 130 + 0], w1 = tile[t * 130 + 1];
        const float bb = 2.f * b1[cell * Hh + t];
        o.h[0] = (f16)(2.f * w1 + bb);
        o.h[1] = (f16)(w0 + w1 + bb);
        o.h[2] = (f16)(2.f * w0 + bb);
        o.h[3] = (f16)Wf[cell * Hh + t];
        *(u32x2*)(dst + 32768 + t * 8) = o.v;
    }
}

// 512 blocks x 1 batch element, 2 blocks/CU (round-5 champion structure,
// 960us) with the pre-barrier critical path stripped: the head DPP reduce
// and the lp exp/log chain run ONE CELL LATE in the post-barrier "shadow",
// overlapping the next cell's inp-read LDS latency. Critical path per cell
// is now: barrier -> inp reads issue -> vmcnt(18) -> 32 dot2 -> combine ->
// tanh -> exchange write -> barrier. s_setprio(1) wraps the critical
// section (the 2 co-resident blocks are phase-offset -> arbitration helps).
// Weights: 4 rotating asm-volatile register buffers (proven safe at this
// VGPR pressure), counted vmcnt(18) retirement — never a drain.
__global__ __launch_bounds__(256, 2)
void rnn2d(const float* __restrict__ samples,
           const char* __restrict__ Wt,
           const float* __restrict__ bfv,
           float* __restrict__ out)
{
    __shared__ __align__(16) h2  inp[2][64];        // input pairs, dbuffered
    __shared__ __align__(16) f16 hvh[Lr * Hh];      // vertical hidden, 8 KB
    __shared__ float smp[NCELL];
    __shared__ float bfs[NCELL];
    __shared__ __align__(16) float fp_[2][4];       // head partials [cell&1][wave]
    __shared__ int   sidx[2];                       // spin-case 0/1/2 [parity]
    __shared__ float lpb[2];

    const int t    = threadIdx.x;
    const int k    = t >> 1;
    const int half = t & 1;
    const int w    = t >> 6;
    const int b    = blockIdx.x;

    // loop-invariant load offsets (VGPRs)
    u32 vc[8], vt;
    for (int q4 = 0; q4 < 8; ++q4) vc[q4] = (u32)(q4 * 4096 + t * 16);
    vt = (u32)(32768 + k * 8);

    {
        f16* z1 = (f16*)inp;
        for (int idx = t; idx < 2 * 64 * 2; idx += 256) z1[idx] = (f16)0.f;
        f16* z2 = (f16*)hvh;
        for (int idx = t; idx < Lr * Hh; idx += 256) z2[idx] = (f16)0.f;
        for (int idx = t; idx < NCELL; idx += 256) {
            smp[idx] = samples[(size_t)b * NCELL + idx];
            bfs[idx] = bfv[idx];
        }
        if (t == 0) sidx[0] = 0;      // cell 0: xh=xv=0
    }
    float lp = 0.f;
    float hPrev = 0.f, wvPrev = 0.f;   // snapshot for the deferred head

    u32x4 A0,A1,A2,A3,A4,A5,A6,A7, B0,B1,B2,B3,B4,B5,B6,B7;
    u32x4 C0,C1,C2,C3,C4,C5,C6,C7, D0,D1,D2,D3,D4,D5,D6,D7;
    u32x2 TA, TB, TC, TD;

// issue the 9 uniform volatile loads for cell S into one register buffer
#define ISSUE(S, W0,W1_,W2_,W3_,W4_,W5_,W6_,W7_, TT)                        \
    {                                                                       \
        const int s_ = ((S) < NCELL) ? (S) : 0;   /* uniform dummy at tail */\
        const char* cb_ = Wt + (size_t)cell_of(s_) * CELLB;                 \
        asm volatile("global_load_dwordx4 %0, %1, %2" : "=v"(W0)  : "v"(vc[0]), "s"(cb_)); \
        asm volatile("global_load_dwordx4 %0, %1, %2" : "=v"(W1_) : "v"(vc[1]), "s"(cb_)); \
        asm volatile("global_load_dwordx4 %0, %1, %2" : "=v"(W2_) : "v"(vc[2]), "s"(cb_)); \
        asm volatile("global_load_dwordx4 %0, %1, %2" : "=v"(W3_) : "v"(vc[3]), "s"(cb_)); \
        asm volatile("global_load_dwordx4 %0, %1, %2" : "=v"(W4_) : "v"(vc[4]), "s"(cb_)); \
        asm volatile("global_load_dwordx4 %0, %1, %2" : "=v"(W5_) : "v"(vc[5]), "s"(cb_)); \
        asm volatile("global_load_dwordx4 %0, %1, %2" : "=v"(W6_) : "v"(vc[6]), "s"(cb_)); \
        asm volatile("global_load_dwordx4 %0, %1, %2" : "=v"(W7_) : "v"(vc[7]), "s"(cb_)); \
        asm volatile("global_load_dwordx2 %0, %1, %2" : "=v"(TT)  : "v"(vt),    "s"(cb_)); \
    }

#define DOT4R(WQ, XQ)                                                       \
    {                                                                       \
        const u32x4 v_ = (WQ);                                              \
        a00 = dot2(bch2(v_.x), bch2((XQ).x), a00);                          \
        a01 = dot2(bch2(v_.y), bch2((XQ).y), a01);                          \
        a02 = dot2(bch2(v_.z), bch2((XQ).z), a02);                          \
        a03 = dot2(bch2(v_.w), bch2((XQ).w), a03);                          \
    }

#define PROC(S, Q, W0,W1_,W2_,W3_,W4_,W5_,W6_,W7_, TT)                      \
    {                                                                       \
        const int i_ = (S) >> 5, j_ = (S) & 31;                             \
        const int c_ = (i_ & 1) ? (Lr - 1 - j_) : j_;                       \
        const int sn_ = ((S) + 1 < NCELL) ? (S) + 1 : (S);                  \
        const int in_ = sn_ >> 5, jn_ = sn_ & 31;                           \
        const int cn_ = (in_ & 1) ? (Lr - 1 - jn_) : jn_;                   \
        /* phase 0: issue this cell's LDS reads (latency hidden by shadow) */\
        const uint4 xq0 = *(const uint4*)&inp[Q][half * 32 + 0];            \
        const uint4 xq1 = *(const uint4*)&inp[Q][half * 32 + 4];            \
        const uint4 xq2 = *(const uint4*)&inp[Q][half * 32 + 8];            \
        const uint4 xq3 = *(const uint4*)&inp[Q][half * 32 + 12];           \
        const float hvn = (float)hvh[cn_ * Hh + k];                         \
        const int sx = sidx[Q];                                             \
        /* shadow A: deferred head reduce for cell S-1 (off critical path) */\
        if ((S) > 0) {                                                      \
            float fP = hPrev * wvPrev;                                      \
            fP += dpp_get<0x4E>(fP);                                        \
            fP += dpp_get<0x141>(fP);                                       \
            fP += dpp_get<0x140>(fP);                                       \
            fP = fP + rlane(fP, 16) + rlane(fP, 32) + rlane(fP, 48);        \
            if ((t & 63) == 0) fp_[((S) - 1) & 1][w] = fP;                  \
        }                                                                   \
        /* shadow B: deferred log-prob for cell S-2 (lane 4 of waves 2/3; */\
        /* waves 0/1 carry the t==0 bookkeeping -> balanced) */             \
        if (((t & 63) == 4) && (w >= 2) && (S) > 1) {                       \
            const int cp_ = cell_of((S) - 2);                               \
            const float4 fa_ = *(const float4*)&fp_[(S) & 1][0];            \
            const float z_ = ((fa_.x + fa_.y) + (fa_.z + fa_.w)) + bfs[cp_];\
            const float xh_ = 1.f / (1.f + __expf(-z_));                    \
            const float m_ = smp[cp_];                                      \
            lp += (w == 2) ? __logf(xh_ + NEPS) * m_                        \
                           : __logf(1.f - xh_ + NEPS) * (1.f - m_);         \
        }                                                                   \
        /* critical section: weights ready, dot -> tanh -> exchange */      \
        asm volatile("s_waitcnt vmcnt(18)" ::: "memory");                   \
        __builtin_amdgcn_sched_barrier(0);                                  \
        __builtin_amdgcn_s_setprio(1);                                      \
        float a00 = 0.f, a01 = 0.f, a02 = 0.f, a03 = 0.f;                   \
        DOT4R(W0,  xq0) DOT4R(W1_, xq1)                                     \
        DOT4R(W2_, xq2) DOT4R(W3_, xq3)                                     \
        const uint4 xq4 = *(const uint4*)&inp[Q][half * 32 + 16];           \
        const uint4 xq5 = *(const uint4*)&inp[Q][half * 32 + 20];           \
        const uint4 xq6 = *(const uint4*)&inp[Q][half * 32 + 24];           \
        const uint4 xq7 = *(const uint4*)&inp[Q][half * 32 + 28];           \
        DOT4R(W4_, xq4) DOT4R(W5_, xq5)                                     \
        DOT4R(W6_, xq6) DOT4R(W7_, xq7)                                     \
        const float t0_ = h16(TT.x, 0), t1_ = h16(TT.x, 1);                 \
        const float t2_ = h16(TT.y, 0), wfv = h16(TT.y, 1);                 \
        float sp = (sx == 2) ? t2_ : ((sx == 1) ? t1_ : t0_);               \
        if (half) sp = 0.f;                                                 \
        float s0 = ((a00 + a01) + (a02 + a03)) + sp;                        \
        s0 += dpp_get<0xB1>(s0);   /* pair combine: full dot + spin+bias */ \
        const float h0 = fast_tanh(s0);                                     \
        if ((S) + 1 < NCELL) {                                              \
            const float v0 = ((jn_ == 0) ? 0.f : h0)                        \
                           + ((cn_ == c_) ? h0 : hvn);                      \
            const float v0p = dpp_get<0x4E>(v0);  /* partner k's value */   \
            if ((t & 3) == 0) {                                             \
                h2 u0; u0.x = (f16)v0; u0.y = (f16)v0p;                     \
                inp[(Q) ^ 1][t >> 2] = u0;                                  \
            }                                                               \
            if (t == 0) {                                                   \
                const float xh0 = (jn_ == 0) ? 0.f : smp[i_ * Lr + c_];     \
                const float xv0 = (in_ == 0) ? 0.f                          \
                                             : smp[(in_ - 1) * Lr + cn_];   \
                sidx[(Q) ^ 1] = (int)(xh0 + xv0);                           \
            }                                                               \
        }                                                                   \
        hvh[c_ * Hh + k] = (f16)h0;     /* k-partitioned: race-free */      \
        __builtin_amdgcn_s_setprio(0);                                      \
        hPrev = h0; wvPrev = wfv;       /* snapshot for next cell's shadow */\
        bar_lds();   /* single LDS barrier per cell; vmcnt untouched */     \
    }

    // prologue: buffers for cells 0 and 1 in flight; first in-loop wait
    // (vmcnt 18 = B's 9 + C's 9) guarantees buffer A (cell 0) has landed.
    ISSUE(0, A0,A1,A2,A3,A4,A5,A6,A7, TA);
    ISSUE(1, B0,B1,B2,B3,B4,B5,B6,B7, TB);
    __syncthreads();

    for (int s = 0; s < NCELL; s += 4) {
        ISSUE(s + 2, C0,C1,C2,C3,C4,C5,C6,C7, TC);
        PROC(s,     0, A0,A1,A2,A3,A4,A5,A6,A7, TA);
        ISSUE(s + 3, D0,D1,D2,D3,D4,D5,D6,D7, TD);
        PROC(s + 1, 1, B0,B1,B2,B3,B4,B5,B6,B7, TB);
        ISSUE(s + 4, A0,A1,A2,A3,A4,A5,A6,A7, TA);
        PROC(s + 2, 0, C0,C1,C2,C3,C4,C5,C6,C7, TC);
        ISSUE(s + 5, B0,B1,B2,B3,B4,B5,B6,B7, TB);
        PROC(s + 3, 1, D0,D1,D2,D3,D4,D5,D6,D7, TD);
    }
#undef ISSUE
#undef DOT4R
#undef PROC

    // tail: head for cell 1023 (snapshot regs), then lp for cells 1022/1023
    {
        float fP = hPrev * wvPrev;
        fP += dpp_get<0x4E>(fP);
        fP += dpp_get<0x141>(fP);
        fP += dpp_get<0x140>(fP);
        fP = fP + rlane(fP, 16) + rlane(fP, 32) + rlane(fP, 48);
        if ((t & 63) == 0) fp_[1][w] = fP;     // 1023 & 1
    }
    __syncthreads();   // publish fp_[1] (head 1023) and fp_[0] (head 1022)
    if (((t & 63) == 4) && (w >= 2)) {
        for (int cIdx = 0; cIdx < 2; ++cIdx) {         // cells 1022, 1023
            const int cp_ = cell_of(NCELL - 2 + cIdx);
            const float4 fa_ = *(const float4*)&fp_[cIdx][0];
            const float z_ = ((fa_.x + fa_.y) + (fa_.z + fa_.w)) + bfs[cp_];
            const float xh_ = 1.f / (1.f + __expf(-z_));
            const float m_ = smp[cp_];
            lp += (w == 2) ? __logf(xh_ + NEPS) * m_
                           : __logf(1.f - xh_ + NEPS) * (1.f - m_);
        }
        lpb[w - 2] = lp;
    }
    __syncthreads();
    if (t == 0) out[b] = lpb[0] + lpb[1];
}

extern "C" void kernel_launch(void* const* d_in, const int* in_sizes, int n_in,
                              void* d_out, int out_size, void* d_ws, size_t ws_size,
                              hipStream_t stream) {
    const float* samples = (const float*)d_in[0];
    const float* W1      = (const float*)d_in[1];
    const float* b1      = (const float*)d_in[2];
    const float* Wf      = (const float*)d_in[3];
    const float* bf      = (const float*)d_in[4];
    float* outp = (float*)d_out;
    char* Wt = (char*)d_ws;   // 1024 * 33792 B = 34.6 MB

    transpose_w<<<1024, 256, 0, stream>>>(W1, b1, Wf, Wt);
    rnn2d<<<512, 256, 0, stream>>>(samples, Wt, bf, outp);
}